// Round 19
// baseline (216.353 us; speedup 1.0000x reference)
//
#include <hip/hip_runtime.h>
#include <hip/hip_bf16.h>
#include <math.h>

#define SS 128
#define BB 32
#define VV 32000
#define EE 32
#define HH 16
#define KK 32                 // 2*HH = GEMM K
#define NROWS (SS*BB)         // 4096
#define NSL 16                // sumexp vocab slices per row-tile
#define VT 125                // sumexp tiles per slice
#define NPRE 8                // rnn x-prefetch depth
#define WSL 40                // write slices
#define WVT 50                // tiles per write-slice (40*50*16 = 32000)
#define WU 5                  // work-units (rtg,sl) per write block

typedef __attribute__((ext_vector_type(4))) float f32x4;
typedef __attribute__((ext_vector_type(8))) short bf16x8;
typedef __attribute__((ext_vector_type(4))) short s16x4;

#define DPPF(x, ctrl) __builtin_bit_cast(float, __builtin_amdgcn_update_dpp( \
    __builtin_bit_cast(int, (x)), __builtin_bit_cast(int, (x)), (ctrl), 0xF, 0xF, false))

// ------------------------------------------------------------------
// Prep: blocks 0..999 convert W_ho->bf16; blocks 1000..1511 do xproj.
// ------------------------------------------------------------------
__global__ __launch_bounds__(256) void k_prep(
    const float* __restrict__ Who, __hip_bfloat16* __restrict__ who_bf,
    const int* __restrict__ tok, const float* __restrict__ emb,
    const float* __restrict__ Wlr, const float* __restrict__ blr,
    const float* __restrict__ Wrl, const float* __restrict__ brl,
    float* __restrict__ xp) {
  if (blockIdx.x < 1000) {
    int i = blockIdx.x * 256 + threadIdx.x;
    f32x4 v = ((const f32x4*)Who)[i];
    s16x4 o;
    #pragma unroll
    for (int q = 0; q < 4; ++q) {
      __hip_bfloat16 h = __float2bfloat16(v[q]);
      o[q] = *reinterpret_cast<short*>(&h);
    }
    ((s16x4*)who_bf)[i] = o;
  } else {
    int g = (blockIdx.x - 1000) * 256 + threadIdx.x;
    int dir = g >> 16;
    int rem = g & 65535;
    int t = rem >> 9;
    int b = (rem >> 4) & 31;
    int j = rem & 15;
    const float* W  = dir ? Wrl : Wlr;
    const float* bv = dir ? brl : blr;
    int tk = tok[t*BB + b];
    const float* er = emb + tk*EE;
    const float* wr = W + j*(EE+HH);
    float acc = bv[j];
    #pragma unroll
    for (int k = 0; k < EE; ++k) acc += er[k] * wr[k];
    xp[g] = acc;
  }
}

// ------------------------------------------------------------------
// RNN: DPP butterfly + 8-deep register-ring x prefetch (R13/R10 form).
// ------------------------------------------------------------------
__global__ __launch_bounds__(128) void k_rnn_fused(
    const float* __restrict__ xp,
    const float* __restrict__ h0lr, const float* __restrict__ h0rl,
    const float* __restrict__ Wlr, const float* __restrict__ Wrl,
    __hip_bfloat16* __restrict__ comb_bf) {
  int bid = blockIdx.x;
  int dir = bid >> 2;
  int b = (bid & 3) * 8 + (threadIdx.x >> 4);
  int j = threadIdx.x & 15;
  const float* W  = dir ? Wrl : Wlr;
  const float* h0 = dir ? h0rl : h0lr;
  float wr[HH];
  #pragma unroll
  for (int r = 0; r < HH; ++r) wr[r] = W[j*(EE+HH) + EE + (j ^ r)];
  const float* x = xp + dir * (SS*BB*HH);
  int u = b*HH + j;
  float h = h0[u];
  if (dir == 0) comb_bf[0*(BB*KK) + b*KK + j] = __float2bfloat16(h);
  else          comb_bf[(SS-1)*(BB*KK) + b*KK + HH + j] = __float2bfloat16(h);
  float xbuf[NPRE];
  #pragma unroll
  for (int p = 0; p < NPRE; ++p) {
    int tt = 1 + p;
    int off = dir ? (SS-tt)*(BB*HH) + u : (tt-1)*(BB*HH) + u;
    xbuf[p] = x[off];
  }
  for (int tc = 1; tc < SS; tc += NPRE) {
    #pragma unroll
    for (int i = 0; i < NPRE; ++i) {
      int t = tc + i;
      if (t < SS) {
        float xv = xbuf[i];
        int tp = t + NPRE;
        int offp = (tp < SS) ? (dir ? (SS-tp)*(BB*HH) + u : (tp-1)*(BB*HH) + u) : u;
        xbuf[i] = x[offp];
        float t1  = DPPF(h, 0xB1);
        float t2  = DPPF(h, 0x4E);
        float t3  = DPPF(h, 0x1B);
        float t7  = DPPF(h, 0x141);
        float t15 = DPPF(h, 0x140);
        float t4  = DPPF(t7, 0x1B);
        float t5  = DPPF(t7, 0x4E);
        float t6  = DPPF(t7, 0xB1);
        float t8  = DPPF(t15, 0x141);
        float t12 = DPPF(t15, 0x1B);
        float t13 = DPPF(t15, 0x4E);
        float t14 = DPPF(t15, 0xB1);
        float t9  = DPPF(t8, 0xB1);
        float t10 = DPPF(t8, 0x4E);
        float t11 = DPPF(t8, 0x1B);
        float a0 = fmaf(wr[0], h,  xv);
        a0 = fmaf(wr[4],  t4,  a0);
        a0 = fmaf(wr[8],  t8,  a0);
        a0 = fmaf(wr[12], t12, a0);
        float a1 = wr[1] * t1;
        a1 = fmaf(wr[5],  t5,  a1);
        a1 = fmaf(wr[9],  t9,  a1);
        a1 = fmaf(wr[13], t13, a1);
        float a2 = wr[2] * t2;
        a2 = fmaf(wr[6],  t6,  a2);
        a2 = fmaf(wr[10], t10, a2);
        a2 = fmaf(wr[14], t14, a2);
        float a3 = wr[3] * t3;
        a3 = fmaf(wr[7],  t7,  a3);
        a3 = fmaf(wr[11], t11, a3);
        a3 = fmaf(wr[15], t15, a3);
        float acc = (a0 + a1) + (a2 + a3);
        float e = __expf(2.f * acc);
        h = fmaf(-2.f, __builtin_amdgcn_rcpf(e + 1.f), 1.f);
        int ci = dir ? ((SS-1-t)*(BB*KK) + b*KK + HH + j)
                     : (t*(BB*KK) + b*KK + j);
        comb_bf[ci] = __float2bfloat16(h);
      }
    }
  }
}

// ------------------------------------------------------------------
// Sum-exp: 4096 waves, XCD-swizzled (R13 verbatim).
// ------------------------------------------------------------------
__global__ __launch_bounds__(256) void k_sumexp(
    const __hip_bfloat16* __restrict__ cb, const __hip_bfloat16* __restrict__ wb,
    const float* __restrict__ bho, float* __restrict__ part) {
  int wg = ((blockIdx.x & 7) << 7) | (blockIdx.x >> 3);
  int w = wg * 4 + (threadIdx.x >> 6);
  int lane = threadIdx.x & 63;
  int rt = w >> 4;
  int sl = w & 15;
  int v0 = sl * (VT*16);
  int g = lane >> 4, c = lane & 15;
  bf16x8 bfr = *(const bf16x8*)(cb + (size_t)(rt*16 + c)*KK + g*8);
  float s = 0.f;
  for (int t = 0; t < VT; ++t) {
    int v = v0 + t*16;
    bf16x8 af = *(const bf16x8*)(wb + (size_t)(v + c)*KK + g*8);
    f32x4 bh = *(const f32x4*)(bho + v + g*4);
    f32x4 d = __builtin_amdgcn_mfma_f32_16x16x32_bf16(af, bfr, bh, 0, 0, 0);
    s += __expf(d[0]) + __expf(d[1]) + __expf(d[2]) + __expf(d[3]);
  }
  s += __shfl_xor(s, 16);
  s += __shfl_xor(s, 32);
  if (lane < 16)
    part[(size_t)(rt*16 + lane)*NSL + sl] = s;
}

// ------------------------------------------------------------------
// Write: PERSISTENT-SLICE form. Grid 512 = exactly 2 blocks/CU in ONE
// uniform round (no round tails). Each block walks 5 slice-major work
// units (rtg, sl); the W panel is re-staged only when sl changes
// (~552 stagings total vs 2560 in R13). Store loop identical to R13:
// ds_read -> MFMA -> store, zero vmcnt waits. XCD swizzle gives each
// XCD one contiguous 512-row (64MB) output band.
// ------------------------------------------------------------------
__global__ __launch_bounds__(256) void k_write(
    const __hip_bfloat16* __restrict__ cb, const __hip_bfloat16* __restrict__ wb,
    const float* __restrict__ bho, const float* __restrict__ part,
    float* __restrict__ out) {
  __shared__ char afl[WVT * 1024];     // 50 tiles x 1KB, 16B-unit swizzled
  __shared__ float bhl[WVT * 16];      // 800 floats
  int bid = blockIdx.x;                // 0..511
  int k = ((bid & 7) << 6) | (bid >> 3);   // XCD swizzle (512 = 8*64)
  int tid = threadIdx.x;
  int wid = tid >> 6, lane = tid & 63;
  int g = lane >> 4, c = lane & 15;
  int u0 = c*4 + g;
  int us0 = u0 ^ ((u0 >> 3) & 7);
  const char* afp = afl + us0*16;
  int cur_sl = -1;
  for (int ui = 0; ui < WU; ++ui) {
    int u = k*WU + ui;                 // 0..2559, slice-major: u = sl*64 + rtg
    int sl = u >> 6;
    int rtg = u & 63;
    int v0 = sl * (WVT*16);
    if (sl != cur_sl) {
      __syncthreads();                 // prior unit's LDS reads done
      const f32x4* src = (const f32x4*)(wb + (size_t)v0 * KK);
      for (int o = tid; o < WVT*64; o += 256) {
        f32x4 v = src[o];
        int t = o >> 6, uu = o & 63;
        int us = uu ^ ((uu >> 3) & 7);
        *(f32x4*)(afl + t*1024 + us*16) = v;
      }
      for (int o = tid; o < WVT*16; o += 256) bhl[o] = bho[v0 + o];
      __syncthreads();
      cur_sl = sl;
    }
    int rt = rtg*4 + wid;
    size_t row = (size_t)rt*16 + c;
    const f32x4* pp = (const f32x4*)(part + row*NSL);
    f32x4 p0 = pp[0], p1 = pp[1], p2 = pp[2], p3 = pp[3];
    float s = (p0[0]+p0[1]+p0[2]+p0[3]) + (p1[0]+p1[1]+p1[2]+p1[3])
            + (p2[0]+p2[1]+p2[2]+p2[3]) + (p3[0]+p3[1]+p3[2]+p3[3]);
    float Lr = logf(s);
    bf16x8 bfr = *(const bf16x8*)(cb + row*KK + g*8);
    float* op = out + row*VV + v0 + g*4;
    for (int t = 0; t < WVT; ++t) {
      bf16x8 a = *(const bf16x8*)(afp + t*1024);
      f32x4 bh = *(const f32x4*)(bhl + t*16 + g*4);
      f32x4 cin = bh - Lr;
      f32x4 d = __builtin_amdgcn_mfma_f32_16x16x32_bf16(a, bfr, cin, 0, 0, 0);
      *(f32x4*)(op + t*16) = d;
    }
  }
}

// ------------------------------------------------------------------
extern "C" void kernel_launch(void* const* d_in, const int* in_sizes, int n_in,
                              void* d_out, int out_size, void* d_ws, size_t ws_size,
                              hipStream_t stream) {
  const int*   tok  = (const int*)d_in[0];
  const float* h0lr = (const float*)d_in[1];
  const float* h0rl = (const float*)d_in[2];
  const float* emb  = (const float*)d_in[3];
  const float* Wlr  = (const float*)d_in[4];
  const float* blr  = (const float*)d_in[5];
  const float* Wrl  = (const float*)d_in[6];
  const float* brl  = (const float*)d_in[7];
  const float* Who  = (const float*)d_in[8];
  const float* bho  = (const float*)d_in[9];
  float* out = (float*)d_out;
  float* ws  = (float*)d_ws;

  float* xp   = ws;                                           // 131072 floats
  float* part = ws + 131072;                                  // 65536 floats
  __hip_bfloat16* comb_bf = (__hip_bfloat16*)(ws + 196608);   // 131072 bf16
  __hip_bfloat16* who_bf  = (__hip_bfloat16*)(ws + 262144);   // 1024000 bf16

  hipLaunchKernelGGL(k_prep, dim3(1512), dim3(256), 0, stream,
                     Who, who_bf, tok, emb, Wlr, blr, Wrl, brl, xp);
  hipLaunchKernelGGL(k_rnn_fused, dim3(8), dim3(128), 0, stream,
                     xp, h0lr, h0rl, Wlr, Wrl, comb_bf);
  hipLaunchKernelGGL(k_sumexp, dim3(1024), dim3(256), 0, stream,
                     comb_bf, who_bf, bho, part);
  hipLaunchKernelGGL(k_write, dim3(512), dim3(256), 0, stream,
                     comb_bf, who_bf, bho, part, out);
}

// Round 20
// 191.904 us; speedup vs baseline: 1.1274x; 1.1274x over previous
//
#include <hip/hip_runtime.h>
#include <hip/hip_bf16.h>
#include <math.h>

#define SS 128
#define BB 32
#define VV 32000
#define EE 32
#define HH 16
#define KK 32                 // 2*HH = GEMM K
#define NROWS (SS*BB)         // 4096
#define NSL 16                // sumexp vocab slices per row-tile
#define VT 125                // sumexp tiles per slice
#define NPRE 8                // rnn x-prefetch depth
#define WSL 40                // write slices (R13 geometry)
#define WVT 50                // tiles per write-slice (40*50*16 = 32000)

typedef __attribute__((ext_vector_type(4))) float f32x4;
typedef __attribute__((ext_vector_type(8))) short bf16x8;
typedef __attribute__((ext_vector_type(4))) short s16x4;

#define DPPF(x, ctrl) __builtin_bit_cast(float, __builtin_amdgcn_update_dpp( \
    __builtin_bit_cast(int, (x)), __builtin_bit_cast(int, (x)), (ctrl), 0xF, 0xF, false))

// ------------------------------------------------------------------
// Prep: xproj only (512 blocks x 256). W_ho convert moved into the
// rnn dispatch (it was serializing ~8us; now hidden under the rnn).
// ------------------------------------------------------------------
__global__ __launch_bounds__(256) void k_prep(
    const int* __restrict__ tok, const float* __restrict__ emb,
    const float* __restrict__ Wlr, const float* __restrict__ blr,
    const float* __restrict__ Wrl, const float* __restrict__ brl,
    float* __restrict__ xp) {
  int g = blockIdx.x * 256 + threadIdx.x;   // < 131072
  int dir = g >> 16;
  int rem = g & 65535;
  int t = rem >> 9;
  int b = (rem >> 4) & 31;
  int j = rem & 15;
  const float* W  = dir ? Wrl : Wlr;
  const float* bv = dir ? brl : blr;
  int tk = tok[t*BB + b];
  const float* er = emb + tk*EE;
  const float* wr = W + j*(EE+HH);
  float acc = bv[j];
  #pragma unroll
  for (int k = 0; k < EE; ++k) acc += er[k] * wr[k];
  xp[g] = acc;
}

// ------------------------------------------------------------------
// RNN + convert fused in one dispatch: blocks 0-7 run the DPP
// butterfly recurrence (R13 form, 21us on 8 CUs); blocks 8-1007
// convert W_ho->bf16 (independent work, hidden under the rnn).
// ------------------------------------------------------------------
__global__ __launch_bounds__(128) void k_rnn_conv(
    const float* __restrict__ xp,
    const float* __restrict__ h0lr, const float* __restrict__ h0rl,
    const float* __restrict__ Wlr, const float* __restrict__ Wrl,
    const float* __restrict__ Who, __hip_bfloat16* __restrict__ who_bf,
    __hip_bfloat16* __restrict__ comb_bf) {
  int bid = blockIdx.x;
  if (bid >= 8) {
    // ---- W_ho -> bf16: 256000 f32x4 units, 256 per block ----
    int base = (bid - 8) * 256;
    #pragma unroll
    for (int k = 0; k < 2; ++k) {
      int i = base + k*128 + threadIdx.x;
      f32x4 v = ((const f32x4*)Who)[i];
      s16x4 o;
      #pragma unroll
      for (int q = 0; q < 4; ++q) {
        __hip_bfloat16 h = __float2bfloat16(v[q]);
        o[q] = *reinterpret_cast<short*>(&h);
      }
      ((s16x4*)who_bf)[i] = o;
    }
    return;
  }
  // ---- RNN: DPP butterfly + 8-deep register-ring x prefetch ----
  int dir = bid >> 2;
  int b = (bid & 3) * 8 + (threadIdx.x >> 4);
  int j = threadIdx.x & 15;
  const float* W  = dir ? Wrl : Wlr;
  const float* h0 = dir ? h0rl : h0lr;
  float wr[HH];
  #pragma unroll
  for (int r = 0; r < HH; ++r) wr[r] = W[j*(EE+HH) + EE + (j ^ r)];
  const float* x = xp + dir * (SS*BB*HH);
  int u = b*HH + j;
  float h = h0[u];
  if (dir == 0) comb_bf[0*(BB*KK) + b*KK + j] = __float2bfloat16(h);
  else          comb_bf[(SS-1)*(BB*KK) + b*KK + HH + j] = __float2bfloat16(h);
  float xbuf[NPRE];
  #pragma unroll
  for (int p = 0; p < NPRE; ++p) {
    int tt = 1 + p;
    int off = dir ? (SS-tt)*(BB*HH) + u : (tt-1)*(BB*HH) + u;
    xbuf[p] = x[off];
  }
  for (int tc = 1; tc < SS; tc += NPRE) {
    #pragma unroll
    for (int i = 0; i < NPRE; ++i) {
      int t = tc + i;
      if (t < SS) {
        float xv = xbuf[i];
        int tp = t + NPRE;
        int offp = (tp < SS) ? (dir ? (SS-tp)*(BB*HH) + u : (tp-1)*(BB*HH) + u) : u;
        xbuf[i] = x[offp];
        float t1  = DPPF(h, 0xB1);
        float t2  = DPPF(h, 0x4E);
        float t3  = DPPF(h, 0x1B);
        float t7  = DPPF(h, 0x141);
        float t15 = DPPF(h, 0x140);
        float t4  = DPPF(t7, 0x1B);
        float t5  = DPPF(t7, 0x4E);
        float t6  = DPPF(t7, 0xB1);
        float t8  = DPPF(t15, 0x141);
        float t12 = DPPF(t15, 0x1B);
        float t13 = DPPF(t15, 0x4E);
        float t14 = DPPF(t15, 0xB1);
        float t9  = DPPF(t8, 0xB1);
        float t10 = DPPF(t8, 0x4E);
        float t11 = DPPF(t8, 0x1B);
        float a0 = fmaf(wr[0], h,  xv);
        a0 = fmaf(wr[4],  t4,  a0);
        a0 = fmaf(wr[8],  t8,  a0);
        a0 = fmaf(wr[12], t12, a0);
        float a1 = wr[1] * t1;
        a1 = fmaf(wr[5],  t5,  a1);
        a1 = fmaf(wr[9],  t9,  a1);
        a1 = fmaf(wr[13], t13, a1);
        float a2 = wr[2] * t2;
        a2 = fmaf(wr[6],  t6,  a2);
        a2 = fmaf(wr[10], t10, a2);
        a2 = fmaf(wr[14], t14, a2);
        float a3 = wr[3] * t3;
        a3 = fmaf(wr[7],  t7,  a3);
        a3 = fmaf(wr[11], t11, a3);
        a3 = fmaf(wr[15], t15, a3);
        float acc = (a0 + a1) + (a2 + a3);
        float e = __expf(2.f * acc);
        h = fmaf(-2.f, __builtin_amdgcn_rcpf(e + 1.f), 1.f);
        int ci = dir ? ((SS-1-t)*(BB*KK) + b*KK + HH + j)
                     : (t*(BB*KK) + b*KK + j);
        comb_bf[ci] = __float2bfloat16(h);
      }
    }
  }
}

// ------------------------------------------------------------------
// Sum-exp: 4096 waves, XCD-swizzled (R13 verbatim).
// ------------------------------------------------------------------
__global__ __launch_bounds__(256) void k_sumexp(
    const __hip_bfloat16* __restrict__ cb, const __hip_bfloat16* __restrict__ wb,
    const float* __restrict__ bho, float* __restrict__ part) {
  int wg = ((blockIdx.x & 7) << 7) | (blockIdx.x >> 3);
  int w = wg * 4 + (threadIdx.x >> 6);
  int lane = threadIdx.x & 63;
  int rt = w >> 4;
  int sl = w & 15;
  int v0 = sl * (VT*16);
  int g = lane >> 4, c = lane & 15;
  bf16x8 bfr = *(const bf16x8*)(cb + (size_t)(rt*16 + c)*KK + g*8);
  float s = 0.f;
  for (int t = 0; t < VT; ++t) {
    int v = v0 + t*16;
    bf16x8 af = *(const bf16x8*)(wb + (size_t)(v + c)*KK + g*8);
    f32x4 bh = *(const f32x4*)(bho + v + g*4);
    f32x4 d = __builtin_amdgcn_mfma_f32_16x16x32_bf16(af, bfr, bh, 0, 0, 0);
    s += __expf(d[0]) + __expf(d[1]) + __expf(d[2]) + __expf(d[3]);
  }
  s += __shfl_xor(s, 16);
  s += __shfl_xor(s, 32);
  if (lane < 16)
    part[(size_t)(rt*16 + lane)*NSL + sl] = s;
}

// ------------------------------------------------------------------
// Write: R13 verbatim — LDS-staged W panel, vmcnt-decoupled stores,
// 2560 blocks (5 rounds at 2 blocks/CU), XCD-swizzled.
// ------------------------------------------------------------------
__global__ __launch_bounds__(256) void k_write(
    const __hip_bfloat16* __restrict__ cb, const __hip_bfloat16* __restrict__ wb,
    const float* __restrict__ bho, const float* __restrict__ part,
    float* __restrict__ out) {
  __shared__ char afl[WVT * 1024];     // 50 tiles x 1KB, 16B-unit swizzled
  __shared__ float bhl[WVT * 16];      // 800 floats
  int bid = blockIdx.x;
  int wg = ((bid & 7) * 320) + (bid >> 3);   // bijective XCD swizzle (2560%8==0)
  int rtg = wg / WSL;                  // 0..63
  int sl  = wg % WSL;                  // 0..39
  int v0  = sl * (WVT*16);
  int tid = threadIdx.x;
  const f32x4* src = (const f32x4*)(wb + (size_t)v0 * KK);
  for (int o = tid; o < WVT*64; o += 256) {
    f32x4 v = src[o];
    int t = o >> 6, u = o & 63;
    int us = u ^ ((u >> 3) & 7);
    *(f32x4*)(afl + t*1024 + us*16) = v;
  }
  for (int o = tid; o < WVT*16; o += 256) bhl[o] = bho[v0 + o];
  __syncthreads();
  int wid = tid >> 6, lane = tid & 63;
  int rt = rtg*4 + wid;
  int g = lane >> 4, c = lane & 15;
  size_t row = (size_t)rt*16 + c;
  const f32x4* pp = (const f32x4*)(part + row*NSL);
  f32x4 p0 = pp[0], p1 = pp[1], p2 = pp[2], p3 = pp[3];
  float s = (p0[0]+p0[1]+p0[2]+p0[3]) + (p1[0]+p1[1]+p1[2]+p1[3])
          + (p2[0]+p2[1]+p2[2]+p2[3]) + (p3[0]+p3[1]+p3[2]+p3[3]);
  float Lr = logf(s);
  bf16x8 bfr = *(const bf16x8*)(cb + row*KK + g*8);
  int u = c*4 + g;
  int us = u ^ ((u >> 3) & 7);
  const char* afp = afl + us*16;
  float* op = out + row*VV + v0 + g*4;
  for (int t = 0; t < WVT; ++t) {
    bf16x8 a = *(const bf16x8*)(afp + t*1024);
    f32x4 bh = *(const f32x4*)(bhl + t*16 + g*4);
    f32x4 cin = bh - Lr;
    f32x4 d = __builtin_amdgcn_mfma_f32_16x16x32_bf16(a, bfr, cin, 0, 0, 0);
    *(f32x4*)(op + t*16) = d;
  }
}

// ------------------------------------------------------------------
extern "C" void kernel_launch(void* const* d_in, const int* in_sizes, int n_in,
                              void* d_out, int out_size, void* d_ws, size_t ws_size,
                              hipStream_t stream) {
  const int*   tok  = (const int*)d_in[0];
  const float* h0lr = (const float*)d_in[1];
  const float* h0rl = (const float*)d_in[2];
  const float* emb  = (const float*)d_in[3];
  const float* Wlr  = (const float*)d_in[4];
  const float* blr  = (const float*)d_in[5];
  const float* Wrl  = (const float*)d_in[6];
  const float* brl  = (const float*)d_in[7];
  const float* Who  = (const float*)d_in[8];
  const float* bho  = (const float*)d_in[9];
  float* out = (float*)d_out;
  float* ws  = (float*)d_ws;

  float* xp   = ws;                                           // 131072 floats
  float* part = ws + 131072;                                  // 65536 floats
  __hip_bfloat16* comb_bf = (__hip_bfloat16*)(ws + 196608);   // 131072 bf16
  __hip_bfloat16* who_bf  = (__hip_bfloat16*)(ws + 262144);   // 1024000 bf16

  hipLaunchKernelGGL(k_prep, dim3(512), dim3(256), 0, stream,
                     tok, emb, Wlr, blr, Wrl, brl, xp);
  hipLaunchKernelGGL(k_rnn_conv, dim3(1008), dim3(128), 0, stream,
                     xp, h0lr, h0rl, Wlr, Wrl, Who, who_bf, comb_bf);
  hipLaunchKernelGGL(k_sumexp, dim3(1024), dim3(256), 0, stream,
                     comb_bf, who_bf, bho, part);
  hipLaunchKernelGGL(k_write, dim3(2560), dim3(256), 0, stream,
                     comb_bf, who_bf, bho, part, out);
}